// Round 4
// baseline (182.696 us; speedup 1.0000x reference)
//
#include <hip/hip_runtime.h>

#define B_    8
#define D_IN  256
#define D_HID 1024
#define D_OUT 40000       // = 200*200
#define HW4   10000       // D_OUT/4

typedef float f32x4 __attribute__((ext_vector_type(4)));

// Kernel 1: hT[k*8+b] = leakyrelu(loc[b,:] @ W1[:,k] + b1[k])
__global__ void mlp1_kernel(const float* __restrict__ loc,
                            const float* __restrict__ W1,
                            const float* __restrict__ b1,
                            float* __restrict__ hT) {
    int tid = blockIdx.x * blockDim.x + threadIdx.x;   // 8192 threads
    if (tid >= B_ * D_HID) return;
    int b = tid >> 10;
    int k = tid & 1023;
    float acc = b1[k];
    #pragma unroll 8
    for (int i = 0; i < D_IN; ++i)
        acc += loc[b * D_IN + i] * W1[i * D_HID + k];
    acc = (acc >= 0.0f) ? acc : 0.1f * acc;
    hT[k * B_ + b] = acc;
}

// Kernel 2a: split-K partial, float4 over columns, 64-thread blocks for balance.
// grid = (157, KS): 2512 waves ~ 9.8/CU.
template<int KS>
__global__ void mlp2_partial_kernel(const float* __restrict__ hT,
                                    const float* __restrict__ W2,
                                    float* __restrict__ partial) {
    constexpr int CHUNK = D_HID / KS;
    int j4 = blockIdx.x * 64 + threadIdx.x;
    if (j4 >= HW4) return;
    int ks = blockIdx.y;
    int k0 = ks * CHUNK;
    const f32x4* __restrict__ W24 = (const f32x4*)W2;
    f32x4 acc[B_];
    #pragma unroll
    for (int b = 0; b < B_; ++b) acc[b] = (f32x4)0.0f;
    #pragma unroll 8
    for (int kk = 0; kk < CHUNK; ++kk) {
        int k = k0 + kk;
        f32x4 wv = W24[k * HW4 + j4];               // 16B/lane, coalesced
        const float* __restrict__ h = &hT[k * B_];  // wave-uniform -> scalar
        #pragma unroll
        for (int b = 0; b < B_; ++b)
            acc[b] += wv * h[b];
    }
    f32x4* __restrict__ p4 = (f32x4*)partial;
    #pragma unroll
    for (int b = 0; b < B_; ++b)
        p4[(ks * B_ + b) * HW4 + j4] = acc[b];
}

// Kernel 2b: reduce partials + bias, write 1+w. KS compile-time -> full unroll,
// all KS loads independent and in flight.
template<int KS>
__global__ void mlp2_reduce_kernel(const float* __restrict__ partial,
                                   const float* __restrict__ b2,
                                   float* __restrict__ wmap) {
    int t = blockIdx.x * blockDim.x + threadIdx.x;   // over 80000
    if (t >= B_ * HW4) return;
    int b = t / HW4;
    int j4 = t - b * HW4;
    const f32x4* __restrict__ p4  = (const f32x4*)partial;
    const f32x4* __restrict__ b24 = (const f32x4*)b2;
    f32x4 s = b24[j4] + 1.0f;
    #pragma unroll
    for (int ks = 0; ks < KS; ++ks)
        s += p4[(ks * B_ + b) * HW4 + j4];
    ((f32x4*)wmap)[b * HW4 + j4] = s;
}

// Kernel 3: out = x * wmap_broadcast. One block per (b,c) plane — no division.
__global__ void scale_kernel(const float* __restrict__ x,
                             const float* __restrict__ wmap,
                             float* __restrict__ out) {
    int plane = blockIdx.x;                 // b*256 + c
    int b = plane >> 8;
    const f32x4* __restrict__ x4 = (const f32x4*)x + (size_t)plane * HW4;
    f32x4* __restrict__ o4 = (f32x4*)out + (size_t)plane * HW4;
    const f32x4* __restrict__ w4 = (const f32x4*)wmap + (size_t)b * HW4;
    for (int p = threadIdx.x; p < HW4; p += 256) {
        f32x4 xv = __builtin_nontemporal_load(&x4[p]);
        f32x4 wv = w4[p];                   // L2-resident (1.28 MB)
        __builtin_nontemporal_store(xv * wv, &o4[p]);
    }
}

template<int KS>
static void launch_mlp2(const float* hT, const float* W2, const float* b2,
                        float* partial, float* wmap, hipStream_t stream) {
    dim3 g2(157, KS);
    mlp2_partial_kernel<KS><<<g2, 64, 0, stream>>>(hT, W2, partial);
    mlp2_reduce_kernel<KS><<<(B_ * HW4 + 255) / 256, 256, 0, stream>>>(partial, b2, wmap);
}

extern "C" void kernel_launch(void* const* d_in, const int* in_sizes, int n_in,
                              void* d_out, int out_size, void* d_ws, size_t ws_size,
                              hipStream_t stream) {
    const float* x   = (const float*)d_in[0];
    const float* loc = (const float*)d_in[1];
    const float* W1  = (const float*)d_in[2];
    const float* b1  = (const float*)d_in[3];
    const float* W2  = (const float*)d_in[4];
    const float* b2  = (const float*)d_in[5];
    float* out = (float*)d_out;

    float* hT      = (float*)d_ws;                       // 32 KB
    float* partial = (float*)((char*)d_ws + 32768);

    size_t base = 32768;
    int KS = 1;
    for (int cand = 16; cand >= 1; cand >>= 1) {
        size_t need = base + (size_t)(cand + 1) * B_ * D_OUT * sizeof(float);
        if (need <= ws_size) { KS = cand; break; }
    }
    float* wmap = (float*)((char*)d_ws + base
                           + (size_t)KS * B_ * D_OUT * sizeof(float));

    mlp1_kernel<<<32, 256, 0, stream>>>(loc, W1, b1, hT);

    switch (KS) {
        case 16: launch_mlp2<16>(hT, W2, b2, partial, wmap, stream); break;
        case 8:  launch_mlp2<8> (hT, W2, b2, partial, wmap, stream); break;
        case 4:  launch_mlp2<4> (hT, W2, b2, partial, wmap, stream); break;
        case 2:  launch_mlp2<2> (hT, W2, b2, partial, wmap, stream); break;
        default: launch_mlp2<1> (hT, W2, b2, partial, wmap, stream); break;
    }

    scale_kernel<<<2048, 256, 0, stream>>>(x, wmap, out);
}

// Round 5
// 170.875 us; speedup vs baseline: 1.0692x; 1.0692x over previous
//
#include <hip/hip_runtime.h>

#define B_    8
#define D_IN  256
#define D_HID 1024
#define D_OUT 40000       // = 200*200
#define HW4   10000       // D_OUT/4
#define CHW4  2560000     // 256*200*200/4
#define TOT4  20480000    // 8*CHW4

typedef float f32x4 __attribute__((ext_vector_type(4)));

// Kernel 1: hT[k*8+b] = leakyrelu(loc[b,:] @ W1[:,k] + b1[k])
__global__ void mlp1_kernel(const float* __restrict__ loc,
                            const float* __restrict__ W1,
                            const float* __restrict__ b1,
                            float* __restrict__ hT) {
    int tid = blockIdx.x * blockDim.x + threadIdx.x;   // 8192 threads
    if (tid >= B_ * D_HID) return;
    int b = tid >> 10;
    int k = tid & 1023;
    float acc = b1[k];
    #pragma unroll 8
    for (int i = 0; i < D_IN; ++i)
        acc += loc[b * D_IN + i] * W1[i * D_HID + k];
    acc = (acc >= 0.0f) ? acc : 0.1f * acc;
    hT[k * B_ + b] = acc;
}

// Kernel 2a: split-K partial, float4 over columns, 1-wave blocks, grid (157,KS).
template<int KS>
__global__ void mlp2_partial_kernel(const float* __restrict__ hT,
                                    const float* __restrict__ W2,
                                    float* __restrict__ partial) {
    constexpr int CHUNK = D_HID / KS;
    int j4 = blockIdx.x * 64 + threadIdx.x;
    if (j4 >= HW4) return;
    int ks = blockIdx.y;
    int k0 = ks * CHUNK;
    const f32x4* __restrict__ W24 = (const f32x4*)W2;
    f32x4 acc[B_];
    #pragma unroll
    for (int b = 0; b < B_; ++b) acc[b] = (f32x4)0.0f;
    #pragma unroll 8
    for (int kk = 0; kk < CHUNK; ++kk) {
        int k = k0 + kk;
        f32x4 wv = W24[k * HW4 + j4];               // 16B/lane, coalesced
        const float* __restrict__ h = &hT[k * B_];  // wave-uniform, L1-hit
        #pragma unroll
        for (int b = 0; b < B_; ++b)
            acc[b] += wv * h[b];
    }
    f32x4* __restrict__ p4 = (f32x4*)partial;
    #pragma unroll
    for (int b = 0; b < B_; ++b)
        __builtin_nontemporal_store(acc[b], &p4[(ks * B_ + b) * HW4 + j4]);
}

// Kernel 2b: reduce partials + bias, write 1+w. KS unrolled, loads independent.
template<int KS>
__global__ void mlp2_reduce_kernel(const float* __restrict__ partial,
                                   const float* __restrict__ b2,
                                   float* __restrict__ wmap) {
    int t = blockIdx.x * blockDim.x + threadIdx.x;   // over 80000
    if (t >= B_ * HW4) return;
    int b = t / HW4;
    int j4 = t - b * HW4;
    const f32x4* __restrict__ p4  = (const f32x4*)partial;
    const f32x4* __restrict__ b24 = (const f32x4*)b2;
    f32x4 s = b24[j4] + 1.0f;
    #pragma unroll
    for (int ks = 0; ks < KS; ++ks)
        s += __builtin_nontemporal_load(&p4[(ks * B_ + b) * HW4 + j4]);
    ((f32x4*)wmap)[b * HW4 + j4] = s;     // cached: scale reads it next
}

// Kernel 3: out = x * (1+w). Grid-stride contiguous sweep (fill-kernel pattern):
// adjacent blocks read adjacent 4KB chunks -> one moving ~8MB window, good DRAM
// row-buffer locality. b and in-plane index via magic-mul div/mod (cheap).
__global__ void scale_kernel(const float* __restrict__ x,
                             const float* __restrict__ wmap,
                             float* __restrict__ out) {
    const f32x4* __restrict__ x4 = (const f32x4*)x;
    const f32x4* __restrict__ w4 = (const f32x4*)wmap;
    f32x4* __restrict__ o4 = (f32x4*)out;
    int stride = gridDim.x * blockDim.x;
    for (int i = blockIdx.x * blockDim.x + threadIdx.x; i < TOT4; i += stride) {
        unsigned int b  = (unsigned int)i / CHW4;    // magic-mul
        unsigned int p4 = (unsigned int)i % HW4;     // CHW4 multiple of HW4
        f32x4 xv = __builtin_nontemporal_load(&x4[i]);
        f32x4 wv = w4[b * HW4 + p4];                 // L2-resident (1.28 MB)
        __builtin_nontemporal_store(xv * wv, &o4[i]);
    }
}

template<int KS>
static void launch_mlp2(const float* hT, const float* W2, const float* b2,
                        float* partial, float* wmap, hipStream_t stream) {
    dim3 g2(157, KS);
    mlp2_partial_kernel<KS><<<g2, 64, 0, stream>>>(hT, W2, partial);
    mlp2_reduce_kernel<KS><<<(B_ * HW4 + 255) / 256, 256, 0, stream>>>(partial, b2, wmap);
}

extern "C" void kernel_launch(void* const* d_in, const int* in_sizes, int n_in,
                              void* d_out, int out_size, void* d_ws, size_t ws_size,
                              hipStream_t stream) {
    const float* x   = (const float*)d_in[0];
    const float* loc = (const float*)d_in[1];
    const float* W1  = (const float*)d_in[2];
    const float* b1  = (const float*)d_in[3];
    const float* W2  = (const float*)d_in[4];
    const float* b2  = (const float*)d_in[5];
    float* out = (float*)d_out;

    float* hT      = (float*)d_ws;                       // 32 KB
    float* partial = (float*)((char*)d_ws + 32768);

    size_t base = 32768;
    int KS = 1;
    for (int cand = 16; cand >= 1; cand >>= 1) {
        size_t need = base + (size_t)(cand + 1) * B_ * D_OUT * sizeof(float);
        if (need <= ws_size) { KS = cand; break; }
    }
    float* wmap = (float*)((char*)d_ws + base
                           + (size_t)KS * B_ * D_OUT * sizeof(float));

    mlp1_kernel<<<32, 256, 0, stream>>>(loc, W1, b1, hT);

    switch (KS) {
        case 16: launch_mlp2<16>(hT, W2, b2, partial, wmap, stream); break;
        case 8:  launch_mlp2<8> (hT, W2, b2, partial, wmap, stream); break;
        case 4:  launch_mlp2<4> (hT, W2, b2, partial, wmap, stream); break;
        case 2:  launch_mlp2<2> (hT, W2, b2, partial, wmap, stream); break;
        default: launch_mlp2<1> (hT, W2, b2, partial, wmap, stream); break;
    }

    scale_kernel<<<2048, 256, 0, stream>>>(x, wmap, out);
}

// Round 6
// 164.942 us; speedup vs baseline: 1.1076x; 1.0360x over previous
//
#include <hip/hip_runtime.h>

#define B_    8
#define D_IN  256
#define D_HID 1024
#define D_OUT 40000       // = 200*200
#define HW4   10000       // D_OUT/4
#define CHW4  2560000     // 256*200*200/4
#define TOT4  20480000    // 8*CHW4

typedef float f32x4 __attribute__((ext_vector_type(4)));

// Kernel 1: hT[k*8+b] = leakyrelu(loc[b,:] @ W1[:,k] + b1[k])
// 128 blocks x 256 thr. Block g: b = g>>4, k-range = (g&15)*64 .. +64.
// Wave w covers i in [w*64, w*64+64); LDS reduce across the 4 waves.
__global__ void mlp1_kernel(const float* __restrict__ loc,
                            const float* __restrict__ W1,
                            const float* __restrict__ b1,
                            float* __restrict__ hT) {
    __shared__ float red[256];
    int g    = blockIdx.x;
    int b    = g >> 4;
    int k0   = (g & 15) * 64;
    int w    = threadIdx.x >> 6;
    int lane = threadIdx.x & 63;
    int k    = k0 + lane;

    float acc = 0.0f;
    #pragma unroll 8
    for (int ii = 0; ii < 64; ++ii) {
        int i = w * 64 + ii;
        acc += loc[b * D_IN + i] * W1[i * D_HID + k];   // loc: s_load; W1: 256B coalesced
    }
    red[threadIdx.x] = acc;
    __syncthreads();
    if (w == 0) {
        float s = red[lane] + red[64 + lane] + red[128 + lane] + red[192 + lane];
        s += b1[k];
        s = (s >= 0.0f) ? s : 0.1f * s;
        hT[k * B_ + b] = s;
    }
}

// Kernel 2a: split-K partial, float4 over columns, 1-wave blocks, grid (157,KS).
template<int KS>
__global__ void mlp2_partial_kernel(const float* __restrict__ hT,
                                    const float* __restrict__ W2,
                                    float* __restrict__ partial) {
    constexpr int CHUNK = D_HID / KS;
    int j4 = blockIdx.x * 64 + threadIdx.x;
    if (j4 >= HW4) return;
    int ks = blockIdx.y;
    int k0 = ks * CHUNK;
    const f32x4* __restrict__ W24 = (const f32x4*)W2;
    f32x4 acc[B_];
    #pragma unroll
    for (int b = 0; b < B_; ++b) acc[b] = (f32x4)0.0f;
    #pragma unroll 8
    for (int kk = 0; kk < CHUNK; ++kk) {
        int k = k0 + kk;
        f32x4 wv = __builtin_nontemporal_load(&W24[k * HW4 + j4]); // read-once stream
        const float* __restrict__ h = &hT[k * B_];                 // wave-uniform, L2-hit
        #pragma unroll
        for (int b = 0; b < B_; ++b)
            acc[b] += wv * h[b];
    }
    f32x4* __restrict__ p4 = (f32x4*)partial;
    #pragma unroll
    for (int b = 0; b < B_; ++b)
        __builtin_nontemporal_store(acc[b], &p4[(ks * B_ + b) * HW4 + j4]);
}

// Kernel 2b: reduce partials + bias, write 1+w. KS unrolled, loads independent.
template<int KS>
__global__ void mlp2_reduce_kernel(const float* __restrict__ partial,
                                   const float* __restrict__ b2,
                                   float* __restrict__ wmap) {
    int t = blockIdx.x * blockDim.x + threadIdx.x;   // over 80000
    if (t >= B_ * HW4) return;
    int b = t / HW4;
    int j4 = t - b * HW4;
    const f32x4* __restrict__ p4  = (const f32x4*)partial;
    const f32x4* __restrict__ b24 = (const f32x4*)b2;
    f32x4 s = b24[j4] + 1.0f;
    #pragma unroll
    for (int ks = 0; ks < KS; ++ks)
        s += __builtin_nontemporal_load(&p4[(ks * B_ + b) * HW4 + j4]);
    ((f32x4*)wmap)[b * HW4 + j4] = s;     // cached: scale reads it next
}

// Kernel 3: out = x * (1+w). Grid-stride contiguous sweep: adjacent blocks read
// adjacent 4KB chunks -> one moving window, good DRAM row-buffer locality.
__global__ void scale_kernel(const float* __restrict__ x,
                             const float* __restrict__ wmap,
                             float* __restrict__ out) {
    const f32x4* __restrict__ x4 = (const f32x4*)x;
    const f32x4* __restrict__ w4 = (const f32x4*)wmap;
    f32x4* __restrict__ o4 = (f32x4*)out;
    int stride = gridDim.x * blockDim.x;
    for (int i = blockIdx.x * blockDim.x + threadIdx.x; i < TOT4; i += stride) {
        unsigned int b  = (unsigned int)i / CHW4;    // magic-mul
        unsigned int p4 = (unsigned int)i % HW4;     // CHW4 multiple of HW4
        f32x4 xv = __builtin_nontemporal_load(&x4[i]);
        f32x4 wv = w4[b * HW4 + p4];                 // L2-resident (1.28 MB)
        __builtin_nontemporal_store(xv * wv, &o4[i]);
    }
}

template<int KS>
static void launch_mlp2(const float* hT, const float* W2, const float* b2,
                        float* partial, float* wmap, hipStream_t stream) {
    dim3 g2(157, KS);
    mlp2_partial_kernel<KS><<<g2, 64, 0, stream>>>(hT, W2, partial);
    mlp2_reduce_kernel<KS><<<(B_ * HW4 + 255) / 256, 256, 0, stream>>>(partial, b2, wmap);
}

extern "C" void kernel_launch(void* const* d_in, const int* in_sizes, int n_in,
                              void* d_out, int out_size, void* d_ws, size_t ws_size,
                              hipStream_t stream) {
    const float* x   = (const float*)d_in[0];
    const float* loc = (const float*)d_in[1];
    const float* W1  = (const float*)d_in[2];
    const float* b1  = (const float*)d_in[3];
    const float* W2  = (const float*)d_in[4];
    const float* b2  = (const float*)d_in[5];
    float* out = (float*)d_out;

    float* hT      = (float*)d_ws;                       // 32 KB
    float* partial = (float*)((char*)d_ws + 32768);

    size_t base = 32768;
    int KS = 1;
    for (int cand = 16; cand >= 1; cand >>= 1) {
        size_t need = base + (size_t)(cand + 1) * B_ * D_OUT * sizeof(float);
        if (need <= ws_size) { KS = cand; break; }
    }
    float* wmap = (float*)((char*)d_ws + base
                           + (size_t)KS * B_ * D_OUT * sizeof(float));

    mlp1_kernel<<<128, 256, 0, stream>>>(loc, W1, b1, hT);

    switch (KS) {
        case 16: launch_mlp2<16>(hT, W2, b2, partial, wmap, stream); break;
        case 8:  launch_mlp2<8> (hT, W2, b2, partial, wmap, stream); break;
        case 4:  launch_mlp2<4> (hT, W2, b2, partial, wmap, stream); break;
        case 2:  launch_mlp2<2> (hT, W2, b2, partial, wmap, stream); break;
        default: launch_mlp2<1> (hT, W2, b2, partial, wmap, stream); break;
    }

    scale_kernel<<<2048, 256, 0, stream>>>(x, wmap, out);
}